// Round 1
// baseline (309.989 us; speedup 1.0000x reference)
//
#include <hip/hip_runtime.h>
#include <hip/hip_bf16.h>
#include <stdint.h>

// Problem constants
constexpr int IN_DIM   = 2048;
constexpr int OUT_DIM  = 2048;
constexpr int BATCH    = 4096;
constexpr int KDIM     = 2 * IN_DIM;   // concatenated K: [xn | S] vs [scale_base | Wd]
constexpr float LN_EPS = 1e-5f;

// GEMM geometry: BM=256, BN=128, BK=64 -> grid 16x16 = 256 blocks = 1/CU,
// 512 threads = 8 waves (4M x 2N), per-wave 64x64 output.
#define BM 256
#define BN 128
#define BK 64
constexpr int NK     = KDIM / BK;      // 64 k-tiles
constexpr int ASTAGE = BM * BK;        // 16384 shorts = 32 KB per buffer
constexpr int BSTAGE = BN * BK;        //  8192 shorts = 16 KB per buffer

typedef __attribute__((ext_vector_type(8))) short  short8;  // 8 x bf16 (4 VGPRs)
typedef __attribute__((ext_vector_type(4))) float  f32x4;   // MFMA accumulator

__device__ __forceinline__ unsigned short f2bf(float f) {
  __hip_bfloat16 h = __float2bfloat16(f);
  return *reinterpret_cast<unsigned short*>(&h);
}
__device__ __forceinline__ unsigned pack2bf(float a, float b) {
  return (unsigned)f2bf(a) | ((unsigned)f2bf(b) << 16);
}

// ---------------------------------------------------------------------------
// Kernel 1 (FUSED prep) — unchanged from the verified version.
// blocks [0, BATCH): LayerNorm+RBF rows; blocks [BATCH, ...): B-pack.
// Memory-bound at ~235 MB traffic; near roofline.
// ---------------------------------------------------------------------------
constexpr int SW_F4   = OUT_DIM * IN_DIM * 2;   // float4 count of spline_weight
constexpr int SB_F4   = OUT_DIM * IN_DIM / 4;   // float4 count of scale_base
constexpr int PACK_BLOCKS = (SW_F4 + SB_F4) / 256;

__global__ __launch_bounds__(256) void prep_kernel(
    const float* __restrict__ x, const float* __restrict__ lnw,
    const float* __restrict__ lnb, const float* __restrict__ betap,
    const float* __restrict__ grid, unsigned short* __restrict__ A,
    const float* __restrict__ sw, const float* __restrict__ sb,
    unsigned* __restrict__ Bu)    // B as uint (2 bf16 per uint), OUT x KDIM/2
{
  const int tid = threadIdx.x;
  if (blockIdx.x < BATCH) {
    // ----------------------- LayerNorm + RBF path -----------------------
    const int row = blockIdx.x;
    const float4* xr = reinterpret_cast<const float4*>(x + (size_t)row * IN_DIM);
    float4 v0 = xr[tid];
    float4 v1 = xr[tid + 256];
    float s = (v0.x + v0.y) + (v0.z + v0.w) + (v1.x + v1.y) + (v1.z + v1.w);
    float q = v0.x * v0.x + v0.y * v0.y + v0.z * v0.z + v0.w * v0.w
            + v1.x * v1.x + v1.y * v1.y + v1.z * v1.z + v1.w * v1.w;
    #pragma unroll
    for (int off = 32; off > 0; off >>= 1) {
      s += __shfl_down(s, off, 64);
      q += __shfl_down(q, off, 64);
    }
    __shared__ float red[10];
    const int lane = tid & 63, wv = tid >> 6;
    if (lane == 0) { red[wv] = s; red[4 + wv] = q; }
    __syncthreads();
    if (tid == 0) {
      float ts = (red[0] + red[1]) + (red[2] + red[3]);
      float tq = (red[4] + red[5]) + (red[6] + red[7]);
      float mu  = ts * (1.0f / IN_DIM);
      float var = tq * (1.0f / IN_DIM) - mu * mu;
      red[8] = mu;
      red[9] = rsqrtf(var + LN_EPS);
    }
    __syncthreads();
    const float mu = red[8], rs = red[9];
    const float beta = fminf(fmaxf(betap[0], 0.5f), 6.0f);
    float g[8];
    #pragma unroll
    for (int i = 0; i < 8; i++) g[i] = grid[i];
    const float4* w4 = reinterpret_cast<const float4*>(lnw);
    const float4* b4 = reinterpret_cast<const float4*>(lnb);
    unsigned short* Ar = A + (size_t)row * KDIM;
    #pragma unroll
    for (int h = 0; h < 2; h++) {
      const int idx = tid + h * 256;        // float4 index within the row
      float4 xv  = (h == 0) ? v0 : v1;
      float4 wv4 = w4[idx];
      float4 bv4 = b4[idx];
      float xa[4] = {xv.x, xv.y, xv.z, xv.w};
      float wa[4] = {wv4.x, wv4.y, wv4.z, wv4.w};
      float ba[4] = {bv4.x, bv4.y, bv4.z, bv4.w};
      float xn[4], S[4];
      #pragma unroll
      for (int c = 0; c < 4; c++) {
        float xnv = (xa[c] - mu) * rs * wa[c] + ba[c];
        xn[c] = xnv;
        float acc = 0.f;
        #pragma unroll
        for (int gg = 0; gg < 8; gg++) {
          float d = xnv - g[gg];
          acc += __expf(-beta * d * d);
        }
        S[c] = acc;
      }
      uint2 px, ps;
      px.x = pack2bf(xn[0], xn[1]);
      px.y = pack2bf(xn[2], xn[3]);
      ps.x = pack2bf(S[0], S[1]);
      ps.y = pack2bf(S[2], S[3]);
      *reinterpret_cast<uint2*>(Ar + idx * 4) = px;
      *reinterpret_cast<uint2*>(Ar + IN_DIM + idx * 4) = ps;
    }
  } else {
    // --------------------------- B-pack path ---------------------------
    const int g = (blockIdx.x - BATCH) * 256 + tid;
    const int lane = tid & 63;
    if (g < SW_F4) {
      float4 v = reinterpret_cast<const float4*>(sw)[g];
      float s = (v.x + v.y) + (v.z + v.w);
      s += __shfl_xor(s, 1, 64);               // full Wd[i] in both lanes of pair
      float hi = __shfl_down(s, 2, 64);        // Wd of i+1 for even-pair lanes
      if ((lane & 3) == 0) {
        const int i_lin = g >> 1;              // linear (o,i)
        const int o = i_lin >> 11;             // / IN_DIM
        const int i = i_lin & (IN_DIM - 1);
        Bu[(size_t)o * (KDIM / 2) + (IN_DIM / 2) + (i >> 1)] = pack2bf(s, hi);
      }
    } else {
      const int t = g - SW_F4;                 // [0, SB_F4)
      float4 v = reinterpret_cast<const float4*>(sb)[t];
      const int o  = t >> 9;                   // 512 float4 per sb row
      const int i4 = t & 511;
      uint2 u;
      u.x = pack2bf(v.x, v.y);
      u.y = pack2bf(v.z, v.w);
      *reinterpret_cast<uint2*>(&Bu[(size_t)o * (KDIM / 2) + i4 * 2]) = u;
    }
  }
}

// ---------------------------------------------------------------------------
// Kernel 2: C = A @ B^T + bias.  M=BATCH, N=OUT_DIM, K=KDIM, bf16 MFMA.
// NEW STRUCTURE (T3+T4+T5 on top of the proven T2 addressing):
//   - BM=256 x BN=128 tile, BK=64, 512 thr / 8 waves (4M x 2N, 64x64/wave)
//   - TRIPLE-buffered LDS (144 KB): while computing tile t, stage tile t+2
//     into the buffer freed by tile t-1 -> counted s_waitcnt vmcnt(6) at the
//     tile boundary, never vmcnt(0) in the main loop (T4).
//   - 2 phases per k-tile (k-halves); each phase: 8 ds_read_b128 -> issue 3
//     global_load_lds sweeps -> raw s_barrier -> lgkmcnt(0) -> setprio(1) ->
//     16 MFMA -> setprio(0) -> s_barrier (T3 rhythm, T5 arbitration).
//   - NO __syncthreads() in the loop (it would emit vmcnt(0) and drain the
//     prefetch queue -- the documented ~900 TF ceiling of the old structure).
// Staging swizzle, ds_read addressing, MFMA fragments, C/D layout identical
// to the previous verified kernel (slot s holds global col8 = (s&7)^(row&7)).
// XCD swizzle: 256 blocks, block d -> XCD d&7 [m09]; each XCD gets a 4x8
// (bm,bn) patch -> per-XCD k-slice working set 256 KB, L2-resident.
// ---------------------------------------------------------------------------
__device__ __forceinline__ void gld_lds16(const unsigned short* g, unsigned short* l) {
  __builtin_amdgcn_global_load_lds(
      (const __attribute__((address_space(1))) void*)g,
      (__attribute__((address_space(3))) void*)l, 16, 0, 0);
}

__global__ __launch_bounds__(512, 2) void gemm_kernel(
    const unsigned short* __restrict__ A, const unsigned short* __restrict__ Bm,
    const float* __restrict__ bias, float* __restrict__ out)
{
  __shared__ __align__(16) unsigned short As[3 * ASTAGE];   // 96 KB
  __shared__ __align__(16) unsigned short Bs[3 * BSTAGE];   // 48 KB
  const int tid  = threadIdx.x;
  const int lane = tid & 63;
  const int wv   = tid >> 6;        // 0..7
  const int wr   = wv >> 1;         // 0..3 : M band (64 rows each)
  const int wc   = wv & 1;          // 0..1 : N band (64 cols each)
  const int lrow = lane & 15;       // fragment m / n index
  const int lkq  = lane >> 4;       // k-quarter within a 16B-granule row

  // XCD supertile swizzle (bijective for 256 blocks): XCD x gets a 4x8 patch.
  const int gid = blockIdx.x;
  const int x   = gid & 7;
  const int q   = gid >> 3;                      // 0..31 within XCD
  const int m0  = ((x >> 1) * 4 + (q >> 3)) * BM;  // bm in [0,16)
  const int n0  = ((x & 1) * 8 + (q & 7)) * BN;    // bn in [0,16)

  f32x4 acc[4][4] = {};

  // Staging addresses: sweep = 512 threads x 16 B = 8 KB = 64 rows.
  // A tile = 4 sweeps, B tile = 2 sweeps; 6 loads/thread/k-tile.
  // LDS slot s (granule) holds global col8 = (s&7) ^ (row&7): swizzle folded
  // into the GLOBAL fetch address; LDS dest is wave-uniform base + lane*16.
  const unsigned short* Ag[4];
  const unsigned short* Bg[2];
  int ldsAo[4], ldsBo[2];
  #pragma unroll
  for (int j = 0; j < 4; j++) {
    const int row  = j * 64 + (tid >> 3);
    const int colg = ((tid & 7) ^ (row & 7)) * 8;
    Ag[j]   = A + (size_t)(m0 + row) * KDIM + colg;
    ldsAo[j] = (j * 512 + wv * 64) * 8;
  }
  #pragma unroll
  for (int j = 0; j < 2; j++) {
    const int row  = j * 64 + (tid >> 3);
    const int colg = ((tid & 7) ^ (row & 7)) * 8;
    Bg[j]   = Bm + (size_t)(n0 + row) * KDIM + colg;
    ldsBo[j] = (j * 512 + wv * 64) * 8;
  }

  // Prologue: tiles 0,1 into buffers 0,1 (12 loads/thread); wait so tile 0
  // is landed (vmcnt(6) leaves tile 1's 6 in flight), then barrier.
  #pragma unroll
  for (int j = 0; j < 4; j++) gld_lds16(Ag[j], &As[ldsAo[j]]);
  #pragma unroll
  for (int j = 0; j < 2; j++) gld_lds16(Bg[j], &Bs[ldsBo[j]]);
  #pragma unroll
  for (int j = 0; j < 4; j++) gld_lds16(Ag[j] + BK, &As[ASTAGE + ldsAo[j]]);
  #pragma unroll
  for (int j = 0; j < 2; j++) gld_lds16(Bg[j] + BK, &Bs[BSTAGE + ldsBo[j]]);
  asm volatile("s_waitcnt vmcnt(6)" ::: "memory");
  __builtin_amdgcn_s_barrier();

  int rb_cur = 0;   // buffer of tile t       (= t % 3)
  int rb_pf  = 2;   // buffer of tile t + 2   (= (t+2) % 3, freed by tile t-1)

  #pragma unroll 1
  for (int t = 0; t < NK; ++t) {
    const unsigned short* ar = &As[rb_cur * ASTAGE];
    const unsigned short* br = &Bs[rb_cur * BSTAGE];
    unsigned short*       aw = &As[rb_pf  * ASTAGE];
    unsigned short*       bw = &Bs[rb_pf  * BSTAGE];
    const int  koff = (t + 2) * BK;
    const bool pf   = (t + 2 < NK);

    short8 af[4], bf[4];

    // ---------------- phase 0 (k 0..31) ----------------
    #pragma unroll
    for (int mi = 0; mi < 4; mi++) {
      const int r = wr * 64 + mi * 16 + lrow;
      af[mi] = *reinterpret_cast<const short8*>(
          &ar[r * BK + ((lkq ^ (lrow & 7)) * 8)]);
    }
    #pragma unroll
    for (int ni = 0; ni < 4; ni++) {
      const int r = wc * 64 + ni * 16 + lrow;
      bf[ni] = *reinterpret_cast<const short8*>(
          &br[r * BK + ((lkq ^ (lrow & 7)) * 8)]);
    }
    if (pf) {
      gld_lds16(Ag[0] + koff, &aw[ldsAo[0]]);
      gld_lds16(Ag[1] + koff, &aw[ldsAo[1]]);
      gld_lds16(Bg[0] + koff, &bw[ldsBo[0]]);
    }
    __builtin_amdgcn_s_barrier();
    asm volatile("s_waitcnt lgkmcnt(0)" ::: "memory");
    __builtin_amdgcn_s_setprio(1);
    #pragma unroll
    for (int mi = 0; mi < 4; mi++)
      #pragma unroll
      for (int ni = 0; ni < 4; ni++)
        acc[mi][ni] = __builtin_amdgcn_mfma_f32_16x16x32_bf16(
            af[mi], bf[ni], acc[mi][ni], 0, 0, 0);
    __builtin_amdgcn_s_setprio(0);
    __builtin_amdgcn_s_barrier();

    // ---------------- phase 1 (k 32..63) ----------------
    #pragma unroll
    for (int mi = 0; mi < 4; mi++) {
      const int r = wr * 64 + mi * 16 + lrow;
      af[mi] = *reinterpret_cast<const short8*>(
          &ar[r * BK + (((4 | lkq) ^ (lrow & 7)) * 8)]);
    }
    #pragma unroll
    for (int ni = 0; ni < 4; ni++) {
      const int r = wc * 64 + ni * 16 + lrow;
      bf[ni] = *reinterpret_cast<const short8*>(
          &br[r * BK + (((4 | lkq) ^ (lrow & 7)) * 8)]);
    }
    if (pf) {
      gld_lds16(Ag[2] + koff, &aw[ldsAo[2]]);
      gld_lds16(Ag[3] + koff, &aw[ldsAo[3]]);
      gld_lds16(Bg[1] + koff, &bw[ldsBo[1]]);
    }
    __builtin_amdgcn_s_barrier();
    asm volatile("s_waitcnt lgkmcnt(0)" ::: "memory");
    __builtin_amdgcn_s_setprio(1);
    #pragma unroll
    for (int mi = 0; mi < 4; mi++)
      #pragma unroll
      for (int ni = 0; ni < 4; ni++)
        acc[mi][ni] = __builtin_amdgcn_mfma_f32_16x16x32_bf16(
            af[mi], bf[ni], acc[mi][ni], 0, 0, 0);
    __builtin_amdgcn_s_setprio(0);

    // Tile-boundary wait: tile t+1 must be landed before next iteration reads
    // it. Counted -- tile t+2's 6 loads stay in flight across the barrier.
    if (pf) {
      asm volatile("s_waitcnt vmcnt(6)" ::: "memory");
    } else if (t + 2 == NK) {
      asm volatile("s_waitcnt vmcnt(0)" ::: "memory");   // epilogue drain
    }
    __builtin_amdgcn_s_barrier();

    rb_cur = (rb_cur == 2) ? 0 : rb_cur + 1;
    rb_pf  = (rb_pf  == 2) ? 0 : rb_pf  + 1;
  }

  // Epilogue: C/D layout col=lane&15, row=(lane>>4)*4+reg  [measured m89/m91]
  const int rb = (lane >> 4) * 4;
  #pragma unroll
  for (int ni = 0; ni < 4; ni++) {
    const int col = n0 + wc * 64 + ni * 16 + lrow;
    const float bv = bias[col];
    #pragma unroll
    for (int mi = 0; mi < 4; mi++) {
      const int rowm = m0 + wr * 64 + mi * 16 + rb;
      #pragma unroll
      for (int r = 0; r < 4; r++)
        out[(size_t)(rowm + r) * OUT_DIM + col] = acc[mi][ni][r] + bv;
    }
  }
}

// ---------------------------------------------------------------------------
extern "C" void kernel_launch(void* const* d_in, const int* in_sizes, int n_in,
                              void* d_out, int out_size, void* d_ws, size_t ws_size,
                              hipStream_t stream) {
  const float* x    = (const float*)d_in[0];
  const float* lnw  = (const float*)d_in[1];
  const float* lnb  = (const float*)d_in[2];
  const float* sw   = (const float*)d_in[3];   // (OUT, IN, 8)
  const float* sb   = (const float*)d_in[4];   // (OUT, IN)
  const float* bias = (const float*)d_in[5];   // (OUT,)
  const float* beta = (const float*)d_in[6];   // (1,)
  const float* grid = (const float*)d_in[7];   // (8,)
  float* out = (float*)d_out;

  unsigned short* A = (unsigned short*)d_ws;               // BATCH x KDIM bf16 (33.5 MB)
  unsigned short* B = A + (size_t)BATCH * KDIM;            // OUT   x KDIM bf16 (16.8 MB)

  hipLaunchKernelGGL(prep_kernel, dim3(BATCH + PACK_BLOCKS), dim3(256), 0, stream,
                     x, lnw, lnb, beta, grid, A, sw, sb, (unsigned*)B);
  hipLaunchKernelGGL(gemm_kernel, dim3((BATCH / BM) * (OUT_DIM / BN)), dim3(512), 0, stream,
                     A, B, bias, out);
}